// Round 2
// baseline (831.655 us; speedup 1.0000x reference)
//
#include <hip/hip_runtime.h>

#define NN 768
#define HH 128
#define TJ 32
#define NT (NN / TJ)          // 24 j-tiles
#define THREADS 512

// LDS layout (floats):
//   [0      .. 16384)  eW2 staged   [128][128]
//   [16384  .. 32768)  gW1 staged   [128][128]
//   [32768  .. 36864)  SH           [32][128]   (silu(h1), then raw EH, then reduce scratch)
//   [36864  .. 36896)  dtile        [32]
//   [36896  .. 36992)  dirt         [32][3]
//   [36992  .. 37024)  pmt          [32]
#define SMEM_FLOATS (2 * HH * HH + TJ * HH + TJ + 3 * TJ + TJ)
#define SMEM_BYTES (SMEM_FLOATS * 4)

__device__ __forceinline__ float fast_sig(float x) {
    return __builtin_amdgcn_rcpf(1.0f + __expf(-x));
}
__device__ __forceinline__ float fast_silu(float x) { return x * fast_sig(x); }

#define RANK1(ACC, S, W)                    \
    ACC[0] = fmaf((S), (W).x, ACC[0]);      \
    ACC[1] = fmaf((S), (W).y, ACC[1]);      \
    ACC[2] = fmaf((S), (W).z, ACC[2]);      \
    ACC[3] = fmaf((S), (W).w, ACC[3]);

// ---------------- K1: per-node projections AiP/AjP ----------------
__global__ void precompute_proj(const float* __restrict__ nf,
                                const float* __restrict__ cons,
                                const float* __restrict__ memb,
                                const float* __restrict__ cata,
                                const float* __restrict__ eW1,
                                const float* __restrict__ eb1,
                                float* __restrict__ AiP,
                                float* __restrict__ AjP) {
    __shared__ float row[HH];
    int i = blockIdx.x;
    int h = threadIdx.x;
    row[h] = nf[i * HH + h];
    __syncthreads();
    float ci = cons[i], mi = memb[i], ti = cata[i];
    float ai = eb1[h] + ci * eW1[257 * HH + h] + mi * eW1[259 * HH + h];
    float aj = ci * eW1[258 * HH + h] + ti * eW1[260 * HH + h];
    for (int k = 0; k < HH; ++k) {
        float x = row[k];
        ai = fmaf(x, eW1[k * HH + h], ai);
        aj = fmaf(x, eW1[(HH + k) * HH + h], aj);
    }
    AiP[i * HH + h] = ai;
    AjP[i * HH + h] = aj;
}

// ---------------- K2: main per-row kernel ----------------
__global__ void __launch_bounds__(THREADS)
main_kernel(const float* __restrict__ nf, const float* __restrict__ vf,
            const float* __restrict__ pos, const int* __restrict__ pm,
            const float* __restrict__ eW1, const float* __restrict__ eW2,
            const float* __restrict__ eb2,
            const float* __restrict__ sW1, const float* __restrict__ sb1,
            const float* __restrict__ sW2, const float* __restrict__ sb2,
            const float* __restrict__ gW1, const float* __restrict__ gb1,
            const float* __restrict__ gW2, const float* __restrict__ gb2,
            const float* __restrict__ ln_g, const float* __restrict__ ln_b,
            const float* __restrict__ AiP, const float* __restrict__ AjP,
            float* __restrict__ out_scalar, float* __restrict__ out_vec,
            float* __restrict__ out_ew) {
    extern __shared__ float smem[];
    float* sW2a = smem;                  // [128][128]
    float* sG1a = smem + HH * HH;        // [128][128]
    float* SH   = smem + 2 * HH * HH;    // [32][128]
    float* dtile = SH + TJ * HH;         // [32]
    float* dirt  = dtile + TJ;           // [32][3]
    float* pmt   = dirt + 3 * TJ;        // [32]

    const int t = threadIdx.x;
    const int i = blockIdx.x;
    const int hgrp = t & 31;             // h0 = 4*hgrp
    const int jgrp = t >> 5;             // jj0 = 2*jgrp  (16 groups)
    const int h0 = hgrp * 4;
    const int jj0 = jgrp * 2;

    // stage weights once per block (coalesced float4)
    for (int r = 0; r < (HH * HH) / (THREADS * 4); ++r) {  // 8 reps
        int idx = (r * THREADS + t) * 4;
        *(float4*)&sW2a[idx] = *(const float4*)&eW2[idx];
        *(float4*)&sG1a[idx] = *(const float4*)&gW1[idx];
    }

    // thread-invariant hoists
    const float4 eb2v = *(const float4*)&eb2[h0];
    const float4 gb1v = *(const float4*)&gb1[h0];
    const float4 g2v  = *(const float4*)&gW2[h0];
    const float  gb2s = gb2[0];
    const float pxi = pos[i * 3 + 0], pyi = pos[i * 3 + 1], pzi = pos[i * 3 + 2];

    const float4* SH4 = (const float4*)SH;
    const float4* W4  = (const float4*)sW2a;
    const float4* G4  = (const float4*)sG1a;

    float macc[4] = {0.f, 0.f, 0.f, 0.f};
    float vm0 = 0.f, vm1 = 0.f, vm2 = 0.f;

    for (int jt = 0; jt < NT; ++jt) {
        const int j0 = jt * TJ;
        __syncthreads();  // protect SH/dtile/dirt from previous-iter readers
        if (t < TJ) {
            int j = j0 + t;
            float rx = pxi - pos[j * 3 + 0];
            float ry = pyi - pos[j * 3 + 1];
            float rz = pzi - pos[j * 3 + 2];
            float d = sqrtf(rx * rx + ry * ry + rz * rz);
            d = fmaxf(d, 1e-8f);
            dtile[t] = d;
            float inv = 1.0f / d;
            dirt[t * 3 + 0] = rx * inv;
            dirt[t * 3 + 1] = ry * inv;
            dirt[t * 3 + 2] = rz * inv;
            pmt[t] = (pm[i * NN + j] != 0) ? 1.0f : 0.0f;
        }
        __syncthreads();

        // build S1 = silu(h1) into SH[jj][h]
        for (int r = 0; r < (TJ * HH) / (THREADS * 4); ++r) {  // 2 reps
            int idx = (r * THREADS + t) * 4;
            int jj = idx >> 7;
            int hb = idx & 127;
            int j = j0 + jj;
            float4 a4 = *(const float4*)&AiP[i * HH + hb];
            float4 b4 = *(const float4*)&AjP[j * HH + hb];
            float4 w4 = *(const float4*)&eW1[256 * HH + hb];
            float4 p4 = *(const float4*)&eW1[261 * HH + hb];
            float d = dtile[jj], pf = pmt[jj];
            float4 o;
            o.x = fast_silu(a4.x + b4.x + d * w4.x + pf * p4.x);
            o.y = fast_silu(a4.y + b4.y + d * w4.y + pf * p4.y);
            o.z = fast_silu(a4.z + b4.z + d * w4.z + pf * p4.z);
            o.w = fast_silu(a4.w + b4.w + d * w4.w + pf * p4.w);
            *(float4*)&SH[jj * HH + hb] = o;
        }
        __syncthreads();

        // ---- GEMM1: EH = S1 @ eW2 + eb2 (raw, with bias) ----
        float acc0[4] = {eb2v.x, eb2v.y, eb2v.z, eb2v.w};
        float acc1[4] = {eb2v.x, eb2v.y, eb2v.z, eb2v.w};
#pragma unroll 4
        for (int k4 = 0; k4 < HH / 4; ++k4) {
            float4 s0 = SH4[jj0 * 32 + k4];
            float4 s1 = SH4[(jj0 + 1) * 32 + k4];
            float4 w0 = W4[(k4 * 4 + 0) * 32 + hgrp];
            float4 w1 = W4[(k4 * 4 + 1) * 32 + hgrp];
            float4 w2 = W4[(k4 * 4 + 2) * 32 + hgrp];
            float4 w3 = W4[(k4 * 4 + 3) * 32 + hgrp];
            RANK1(acc0, s0.x, w0); RANK1(acc0, s0.y, w1);
            RANK1(acc0, s0.z, w2); RANK1(acc0, s0.w, w3);
            RANK1(acc1, s1.x, w0); RANK1(acc1, s1.y, w1);
            RANK1(acc1, s1.z, w2); RANK1(acc1, s1.w, w3);
        }

        // row means -> edge weights (butterfly over 32 hgrp lanes in each half-wave)
        float r0 = acc0[0] + acc0[1] + acc0[2] + acc0[3];
        float r1 = acc1[0] + acc1[1] + acc1[2] + acc1[3];
#pragma unroll
        for (int m = 1; m <= 16; m <<= 1) {
            r0 += __shfl_xor(r0, m, 64);
            r1 += __shfl_xor(r1, m, 64);
        }
        float ew0 = fast_sig(r0 * (1.0f / HH)) * pmt[jj0];
        float ew1 = fast_sig(r1 * (1.0f / HH)) * pmt[jj0 + 1];
        if (hgrp == 0) {
            out_ew[i * NN + j0 + jj0 + 0] = ew0;
            out_ew[i * NN + j0 + jj0 + 1] = ew1;
        }
        // message accumulation (per-thread columns h0..h0+3)
        macc[0] += ew0 * acc0[0] + ew1 * acc1[0];
        macc[1] += ew0 * acc0[1] + ew1 * acc1[1];
        macc[2] += ew0 * acc0[2] + ew1 * acc1[2];
        macc[3] += ew0 * acc0[3] + ew1 * acc1[3];

        __syncthreads();  // all GEMM1 SH reads done
        // write RAW edge_hidden (EH) into SH — gate GEMM consumes raw EH;
        // silu is applied AFTER the gW1 matmul (reference semantics).
        {
            *(float4*)&SH[(jj0 + 0) * HH + h0] =
                make_float4(acc0[0], acc0[1], acc0[2], acc0[3]);
            *(float4*)&SH[(jj0 + 1) * HH + h0] =
                make_float4(acc1[0], acc1[1], acc1[2], acc1[3]);
        }
        __syncthreads();

        // ---- GEMM2: G1pre = EH @ gW1 + gb1 ----
        float ga0[4] = {gb1v.x, gb1v.y, gb1v.z, gb1v.w};
        float ga1[4] = {gb1v.x, gb1v.y, gb1v.z, gb1v.w};
#pragma unroll 4
        for (int k4 = 0; k4 < HH / 4; ++k4) {
            float4 s0 = SH4[jj0 * 32 + k4];
            float4 s1 = SH4[(jj0 + 1) * 32 + k4];
            float4 w0 = G4[(k4 * 4 + 0) * 32 + hgrp];
            float4 w1 = G4[(k4 * 4 + 1) * 32 + hgrp];
            float4 w2 = G4[(k4 * 4 + 2) * 32 + hgrp];
            float4 w3 = G4[(k4 * 4 + 3) * 32 + hgrp];
            RANK1(ga0, s0.x, w0); RANK1(ga0, s0.y, w1);
            RANK1(ga0, s0.z, w2); RANK1(ga0, s0.w, w3);
            RANK1(ga1, s1.x, w0); RANK1(ga1, s1.y, w1);
            RANK1(ga1, s1.z, w2); RANK1(ga1, s1.w, w3);
        }
        // g1 = silu(.), dot with gW2 columns, butterfly-reduce over h
        float v0 = fast_silu(ga0[0]) * g2v.x + fast_silu(ga0[1]) * g2v.y +
                   fast_silu(ga0[2]) * g2v.z + fast_silu(ga0[3]) * g2v.w;
        float v1 = fast_silu(ga1[0]) * g2v.x + fast_silu(ga1[1]) * g2v.y +
                   fast_silu(ga1[2]) * g2v.z + fast_silu(ga1[3]) * g2v.w;
#pragma unroll
        for (int m = 1; m <= 16; m <<= 1) {
            v0 += __shfl_xor(v0, m, 64);
            v1 += __shfl_xor(v1, m, 64);
        }
        float vg0 = (v0 + gb2s) * ew0;
        float vg1 = (v1 + gb2s) * ew1;
        if (hgrp == 0) {
            vm0 += vg0 * dirt[jj0 * 3 + 0] + vg1 * dirt[(jj0 + 1) * 3 + 0];
            vm1 += vg0 * dirt[jj0 * 3 + 1] + vg1 * dirt[(jj0 + 1) * 3 + 1];
            vm2 += vg0 * dirt[jj0 * 3 + 2] + vg1 * dirt[(jj0 + 1) * 3 + 2];
        }
    }

    // ---------------- epilogue (per row i) ----------------
    __syncthreads();
    float* mbuf = SH;                 // [16][128]
    float* vbuf = SH + 16 * HH;       // [16][3]
    float* suin = SH + 16 * HH + 64;  // [256]
    float* hbuf = suin + 2 * HH;      // [128]
    float* red  = hbuf + HH;          // [4]
    *(float4*)&mbuf[jgrp * HH + h0] = make_float4(macc[0], macc[1], macc[2], macc[3]);
    if (hgrp == 0) {
        vbuf[jgrp * 3 + 0] = vm0;
        vbuf[jgrp * 3 + 1] = vm1;
        vbuf[jgrp * 3 + 2] = vm2;
    }
    __syncthreads();
    if (t < HH) {
        float m = 0.f;
        for (int g = 0; g < 16; ++g) m += mbuf[g * HH + t];
        suin[t] = nf[i * HH + t];
        suin[HH + t] = m;
    }
    __syncthreads();
    if (t < HH) {
        float a = sb1[t];
        for (int k = 0; k < 2 * HH; ++k) a = fmaf(suin[k], sW1[k * HH + t], a);
        hbuf[t] = fast_silu(a);
    }
    __syncthreads();
    float x = 0.f, sx = 0.f, sq = 0.f;
    if (t < HH) {
        float a = sb2[t];
        for (int k = 0; k < HH; ++k) a = fmaf(hbuf[k], sW2[k * HH + t], a);
        x = nf[i * HH + t] + a;
        sx = x;
        sq = x * x;
    }
#pragma unroll
    for (int m = 1; m <= 32; m <<= 1) {
        sx += __shfl_xor(sx, m, 64);
        sq += __shfl_xor(sq, m, 64);
    }
    if (t == 0)  { red[0] = sx; red[1] = sq; }
    if (t == 64) { red[2] = sx; red[3] = sq; }
    __syncthreads();
    if (t < HH) {
        float mean = (red[0] + red[2]) * (1.0f / HH);
        float var  = (red[1] + red[3]) * (1.0f / HH) - mean * mean;
        out_scalar[i * HH + t] =
            (x - mean) * rsqrtf(var + 1e-5f) * ln_g[t] + ln_b[t];
    }
    if (t < 3) {
        float v = vf[i * 3 + t];
        for (int g = 0; g < 16; ++g) v += vbuf[g * 3 + t];
        out_vec[i * 3 + t] = v;
    }
}

extern "C" void kernel_launch(void* const* d_in, const int* in_sizes, int n_in,
                              void* d_out, int out_size, void* d_ws, size_t ws_size,
                              hipStream_t stream) {
    const float* nf   = (const float*)d_in[0];
    const float* vf   = (const float*)d_in[1];
    const float* pos  = (const float*)d_in[2];
    const int*   pm   = (const int*)d_in[3];
    const float* cons = (const float*)d_in[4];
    const float* memb = (const float*)d_in[5];
    const float* cata = (const float*)d_in[6];
    const float* eW1  = (const float*)d_in[7];
    const float* eb1  = (const float*)d_in[8];
    const float* eW2  = (const float*)d_in[9];
    const float* eb2  = (const float*)d_in[10];
    const float* sW1  = (const float*)d_in[11];
    const float* sb1  = (const float*)d_in[12];
    const float* sW2  = (const float*)d_in[13];
    const float* sb2  = (const float*)d_in[14];
    const float* gW1  = (const float*)d_in[15];
    const float* gb1  = (const float*)d_in[16];
    const float* gW2  = (const float*)d_in[17];
    const float* gb2  = (const float*)d_in[18];
    const float* lng  = (const float*)d_in[19];
    const float* lnb  = (const float*)d_in[20];

    float* out = (float*)d_out;
    float* out_scalar = out;                   // [768*128]
    float* out_vec    = out + NN * HH;         // [768*3]
    float* out_ew     = out + NN * HH + NN * 3;  // [768*768]

    float* AiP = (float*)d_ws;
    float* AjP = AiP + NN * HH;

    precompute_proj<<<NN, HH, 0, stream>>>(nf, cons, memb, cata, eW1, eb1, AiP, AjP);

    hipFuncSetAttribute((const void*)main_kernel,
                        hipFuncAttributeMaxDynamicSharedMemorySize, SMEM_BYTES);
    main_kernel<<<NN, THREADS, SMEM_BYTES, stream>>>(
        nf, vf, pos, pm, eW1, eW2, eb2, sW1, sb1, sW2, sb2, gW1, gb1, gW2, gb2,
        lng, lnb, AiP, AjP, out_scalar, out_vec, out_ew);
}

// Round 4
// 176.420 us; speedup vs baseline: 4.7141x; 4.7141x over previous
//
#include <hip/hip_runtime.h>

#define NN 768
#define HH 128
#define TJ 32
#define NT (NN / TJ)          // 24 j-tiles
#define THREADS 512

typedef __bf16 bf16x8 __attribute__((ext_vector_type(8)));
typedef float f32x4 __attribute__((ext_vector_type(4)));

union U8 { unsigned short s[8]; uint4 u; bf16x8 b; };

__device__ __forceinline__ float fast_sig(float x) {
    return __builtin_amdgcn_rcpf(1.0f + __expf(-x));
}
__device__ __forceinline__ float fast_silu(float x) { return x * fast_sig(x); }

__device__ __forceinline__ unsigned short f2bf(float f) {   // RNE f32->bf16
    unsigned int u = __float_as_uint(f);
    u = (u + 0x7FFFu + ((u >> 16) & 1u)) >> 16;
    return (unsigned short)u;
}

__device__ __forceinline__ f32x4 MFMA(bf16x8 a, bf16x8 b, f32x4 c) {
    return __builtin_amdgcn_mfma_f32_16x16x32_bf16(a, b, c, 0, 0, 0);
}

__device__ __forceinline__ bf16x8 ldfrag(const unsigned short* buf, int off) {
    U8 r;
    r.u = *(const uint4*)((const char*)buf + off);
    return r.b;
}

// ---------------- K1: per-node projections AiP/AjP ----------------
__global__ void precompute_proj(const float* __restrict__ nf,
                                const float* __restrict__ cons,
                                const float* __restrict__ memb,
                                const float* __restrict__ cata,
                                const float* __restrict__ eW1,
                                const float* __restrict__ eb1,
                                float* __restrict__ AiP,
                                float* __restrict__ AjP) {
    __shared__ float row[HH];
    int i = blockIdx.x;
    int h = threadIdx.x;
    row[h] = nf[i * HH + h];
    __syncthreads();
    float ci = cons[i], mi = memb[i], ti = cata[i];
    float ai = eb1[h] + ci * eW1[257 * HH + h] + mi * eW1[259 * HH + h];
    float aj = ci * eW1[258 * HH + h] + ti * eW1[260 * HH + h];
    for (int k = 0; k < HH; ++k) {
        float x = row[k];
        ai = fmaf(x, eW1[k * HH + h], ai);
        aj = fmaf(x, eW1[(HH + k) * HH + h], aj);
    }
    AiP[i * HH + h] = ai;
    AjP[i * HH + h] = aj;
}

// ---------------- K2: main per-row MFMA kernel ----------------
__global__ void __launch_bounds__(THREADS)
main_kernel(const float* __restrict__ nf, const float* __restrict__ vf,
            const float* __restrict__ pos, const int* __restrict__ pm,
            const float* __restrict__ eW1, const float* __restrict__ eW2,
            const float* __restrict__ eb2,
            const float* __restrict__ sW1, const float* __restrict__ sb1,
            const float* __restrict__ sW2, const float* __restrict__ sb2,
            const float* __restrict__ gW1, const float* __restrict__ gb1,
            const float* __restrict__ gW2, const float* __restrict__ gb2,
            const float* __restrict__ ln_g, const float* __restrict__ ln_b,
            const float* __restrict__ AiP, const float* __restrict__ AjP,
            float* __restrict__ out_scalar, float* __restrict__ out_vec,
            float* __restrict__ out_ew) {
    // ---- LDS (all static, ~35 KB) ----
    __shared__ __align__(16) unsigned short S1[TJ * HH];   // bf16, XOR-swizzled
    __shared__ __align__(16) unsigned short EH[TJ * HH];   // bf16, XOR-swizzled
    __shared__ float distL[NN];
    __shared__ float dirxL[NN], diryL[NN], dirzL[NN];
    __shared__ float pmvL[NN];
    __shared__ __align__(16) float ewL[TJ];
    __shared__ float vpart[TJ][4];
    __shared__ float mpart[2][HH];
    __shared__ float vbuf[TJ * 3];
    __shared__ float suin[2 * HH];
    __shared__ float hbuf[HH];
    __shared__ float red2[4];

    const int t = threadIdx.x;
    const int i = blockIdx.x;

    // ---- geometry precompute for row i (once) ----
    {
        const float pxi = pos[i * 3 + 0], pyi = pos[i * 3 + 1], pzi = pos[i * 3 + 2];
        for (int j = t; j < NN; j += THREADS) {
            float rx = pxi - pos[j * 3 + 0];
            float ry = pyi - pos[j * 3 + 1];
            float rz = pzi - pos[j * 3 + 2];
            float d = sqrtf(rx * rx + ry * ry + rz * rz);
            d = fmaxf(d, 1e-8f);
            float inv = 1.0f / d;
            distL[j] = d;
            dirxL[j] = rx * inv;
            diryL[j] = ry * inv;
            dirzL[j] = rz * inv;
            pmvL[j] = (pm[i * NN + j] != 0) ? 1.0f : 0.0f;
        }
    }

    // ---- wave / lane decomposition ----
    const int w = t >> 6, l = t & 63;
    const int m = w & 1;                 // row half (0: rows 0-15, 1: 16-31)
    const int n0 = (w >> 1) * 32;        // col base (two 16-col n-tiles)
    const int lr = l & 15;               // A row / C col index
    const int lg = l >> 4;               // k-group / C row-group
    const int arow = m * 16 + lr;
    const int swzA = (arow & 7) << 4;
    const int aoff0 = ((arow * 256 + 0 * 64 + lg * 16) ^ swzA);
    const int aoff1 = ((arow * 256 + 1 * 64 + lg * 16) ^ swzA);
    const int aoff2 = ((arow * 256 + 2 * 64 + lg * 16) ^ swzA);
    const int aoff3 = ((arow * 256 + 3 * 64 + lg * 16) ^ swzA);

    // ---- B-fragments (block-invariant weights) gathered to registers ----
    auto loadB = [&](const float* __restrict__ W, int nt2, int kc) -> bf16x8 {
        U8 tmp;
        int col = n0 + nt2 * 16 + lr;
#pragma unroll
        for (int e = 0; e < 8; ++e)
            tmp.s[e] = f2bf(W[(kc * 32 + lg * 8 + e) * HH + col]);
        return tmp.b;
    };
    const bf16x8 Bw2_0_0 = loadB(eW2, 0, 0), Bw2_0_1 = loadB(eW2, 0, 1),
                 Bw2_0_2 = loadB(eW2, 0, 2), Bw2_0_3 = loadB(eW2, 0, 3);
    const bf16x8 Bw2_1_0 = loadB(eW2, 1, 0), Bw2_1_1 = loadB(eW2, 1, 1),
                 Bw2_1_2 = loadB(eW2, 1, 2), Bw2_1_3 = loadB(eW2, 1, 3);
    const bf16x8 Bg1_0_0 = loadB(gW1, 0, 0), Bg1_0_1 = loadB(gW1, 0, 1),
                 Bg1_0_2 = loadB(gW1, 0, 2), Bg1_0_3 = loadB(gW1, 0, 3);
    const bf16x8 Bg1_1_0 = loadB(gW1, 1, 0), Bg1_1_1 = loadB(gW1, 1, 1),
                 Bg1_1_2 = loadB(gW1, 1, 2), Bg1_1_3 = loadB(gW1, 1, 3);

    const float eb2a = eb2[n0 + lr], eb2b = eb2[n0 + 16 + lr];
    const float gb1a = gb1[n0 + lr], gb1b = gb1[n0 + 16 + lr];
    const float g2a  = gW2[n0 + lr], g2b  = gW2[n0 + 16 + lr];
    const float gb2s = gb2[0];

    // ---- S1-build hoists (per-thread fixed h-slice) ----
    const int jj_s = t >> 4;                 // 0..31 row of tile
    const int h8 = (t & 15) * 8;             // 8-col slice
    const float4 ai0 = *(const float4*)&AiP[i * HH + h8];
    const float4 ai1 = *(const float4*)&AiP[i * HH + h8 + 4];
    const float4 wd0 = *(const float4*)&eW1[256 * HH + h8];
    const float4 wd1 = *(const float4*)&eW1[256 * HH + h8 + 4];
    const float4 wp0 = *(const float4*)&eW1[261 * HH + h8];
    const float4 wp1 = *(const float4*)&eW1[261 * HH + h8 + 4];
    const int s1woff = ((jj_s * 256 + (t & 15) * 16) ^ ((jj_s & 7) << 4));

    // ew-phase mapping
    const int rrow = t >> 4, rc = t & 15;
    const int roff = ((rrow * 256 + rc * 16) ^ ((rrow & 7) << 4));

    float macc0 = 0.f, macc1 = 0.f;          // message partials (per-lane)
    float vmx = 0.f, vmy = 0.f, vmz = 0.f;   // vector message (t<32)

    for (int jt = 0; jt < NT; ++jt) {
        const int j0 = jt * TJ;
        __syncthreads();   // B1: S1/EH free; prev vpart/ewL ready

        // deferred vector-message step for previous tile
        if (jt > 0 && t < TJ) {
            int jp = j0 - TJ + t;
            float s = vpart[t][0] + vpart[t][1] + vpart[t][2] + vpart[t][3];
            float vg = (s + gb2s) * ewL[t];
            vmx = fmaf(vg, dirxL[jp], vmx);
            vmy = fmaf(vg, diryL[jp], vmy);
            vmz = fmaf(vg, dirzL[jp], vmz);
        }

        // ---- build S1 = silu(h1) tile, bf16, swizzled ----
        {
            int j = j0 + jj_s;
            float4 bj0 = *(const float4*)&AjP[j * HH + h8];
            float4 bj1 = *(const float4*)&AjP[j * HH + h8 + 4];
            float d = distL[j], pf = pmvL[j];
            U8 pk;
            pk.s[0] = f2bf(fast_silu(ai0.x + bj0.x + d * wd0.x + pf * wp0.x));
            pk.s[1] = f2bf(fast_silu(ai0.y + bj0.y + d * wd0.y + pf * wp0.y));
            pk.s[2] = f2bf(fast_silu(ai0.z + bj0.z + d * wd0.z + pf * wp0.z));
            pk.s[3] = f2bf(fast_silu(ai0.w + bj0.w + d * wd0.w + pf * wp0.w));
            pk.s[4] = f2bf(fast_silu(ai1.x + bj1.x + d * wd1.x + pf * wp1.x));
            pk.s[5] = f2bf(fast_silu(ai1.y + bj1.y + d * wd1.y + pf * wp1.y));
            pk.s[6] = f2bf(fast_silu(ai1.z + bj1.z + d * wd1.z + pf * wp1.z));
            pk.s[7] = f2bf(fast_silu(ai1.w + bj1.w + d * wd1.w + pf * wp1.w));
            *(uint4*)((char*)S1 + s1woff) = pk.u;
        }
        __syncthreads();   // B2: S1 ready

        // ---- GEMM1: EH = S1 @ eW2 + eb2 ----
        f32x4 acc0 = {eb2a, eb2a, eb2a, eb2a};
        f32x4 acc1 = {eb2b, eb2b, eb2b, eb2b};
        {
            bf16x8 a0 = ldfrag(S1, aoff0);
            acc0 = MFMA(a0, Bw2_0_0, acc0); acc1 = MFMA(a0, Bw2_1_0, acc1);
            bf16x8 a1 = ldfrag(S1, aoff1);
            acc0 = MFMA(a1, Bw2_0_1, acc0); acc1 = MFMA(a1, Bw2_1_1, acc1);
            bf16x8 a2 = ldfrag(S1, aoff2);
            acc0 = MFMA(a2, Bw2_0_2, acc0); acc1 = MFMA(a2, Bw2_1_2, acc1);
            bf16x8 a3 = ldfrag(S1, aoff3);
            acc0 = MFMA(a3, Bw2_0_3, acc0); acc1 = MFMA(a3, Bw2_1_3, acc1);
        }
        // write raw EH (bf16) to LDS — C/D layout: col=lane&15, row=lg*4+reg
#pragma unroll
        for (int reg = 0; reg < 4; ++reg) {
            int row = m * 16 + lg * 4 + reg;
            int swz = (row & 7) << 4;
            *(unsigned short*)((char*)EH + (((row * 256 + (n0 + lr) * 2)) ^ swz)) =
                f2bf(acc0[reg]);
            *(unsigned short*)((char*)EH + (((row * 256 + (n0 + 16 + lr) * 2)) ^ swz)) =
                f2bf(acc1[reg]);
        }
        __syncthreads();   // B3: EH ready

        // ---- edge weights: row means of EH ----
        {
            uint4 u = *(const uint4*)((const char*)EH + roff);
            float s = __uint_as_float(u.x << 16) + __uint_as_float(u.x & 0xFFFF0000u)
                    + __uint_as_float(u.y << 16) + __uint_as_float(u.y & 0xFFFF0000u)
                    + __uint_as_float(u.z << 16) + __uint_as_float(u.z & 0xFFFF0000u)
                    + __uint_as_float(u.w << 16) + __uint_as_float(u.w & 0xFFFF0000u);
            s += __shfl_xor(s, 1, 16);
            s += __shfl_xor(s, 2, 16);
            s += __shfl_xor(s, 4, 16);
            s += __shfl_xor(s, 8, 16);
            float ewv = fast_sig(s * (1.0f / HH)) * pmvL[j0 + rrow];
            if (rc == 0) {
                ewL[rrow] = ewv;
                out_ew[i * NN + j0 + rrow] = ewv;
            }
        }
        __syncthreads();   // B4: ewL ready

        // ---- message accumulation from accumulators ----
        {
            float4 ew4 = *(const float4*)&ewL[m * 16 + lg * 4];
            macc0 += ew4.x * acc0[0] + ew4.y * acc0[1] + ew4.z * acc0[2] + ew4.w * acc0[3];
            macc1 += ew4.x * acc1[0] + ew4.y * acc1[1] + ew4.z * acc1[2] + ew4.w * acc1[3];
        }

        // ---- GEMM2: G1pre = EH @ gW1 + gb1 ----
        f32x4 g0 = {gb1a, gb1a, gb1a, gb1a};
        f32x4 g1 = {gb1b, gb1b, gb1b, gb1b};
        {
            bf16x8 e0 = ldfrag(EH, aoff0);
            g0 = MFMA(e0, Bg1_0_0, g0); g1 = MFMA(e0, Bg1_1_0, g1);
            bf16x8 e1 = ldfrag(EH, aoff1);
            g0 = MFMA(e1, Bg1_0_1, g0); g1 = MFMA(e1, Bg1_1_1, g1);
            bf16x8 e2 = ldfrag(EH, aoff2);
            g0 = MFMA(e2, Bg1_0_2, g0); g1 = MFMA(e2, Bg1_1_2, g1);
            bf16x8 e3 = ldfrag(EH, aoff3);
            g0 = MFMA(e3, Bg1_0_3, g0); g1 = MFMA(e3, Bg1_1_3, g1);
        }
        // ---- gate: vg-row partial = sum over this wave's 32 cols ----
        {
            float v0 = fast_silu(g0[0]) * g2a + fast_silu(g1[0]) * g2b;
            float v1 = fast_silu(g0[1]) * g2a + fast_silu(g1[1]) * g2b;
            float v2 = fast_silu(g0[2]) * g2a + fast_silu(g1[2]) * g2b;
            float v3 = fast_silu(g0[3]) * g2a + fast_silu(g1[3]) * g2b;
            v0 += __shfl_xor(v0, 1, 16); v0 += __shfl_xor(v0, 2, 16);
            v0 += __shfl_xor(v0, 4, 16); v0 += __shfl_xor(v0, 8, 16);
            v1 += __shfl_xor(v1, 1, 16); v1 += __shfl_xor(v1, 2, 16);
            v1 += __shfl_xor(v1, 4, 16); v1 += __shfl_xor(v1, 8, 16);
            v2 += __shfl_xor(v2, 1, 16); v2 += __shfl_xor(v2, 2, 16);
            v2 += __shfl_xor(v2, 4, 16); v2 += __shfl_xor(v2, 8, 16);
            v3 += __shfl_xor(v3, 1, 16); v3 += __shfl_xor(v3, 2, 16);
            v3 += __shfl_xor(v3, 4, 16); v3 += __shfl_xor(v3, 8, 16);
            if (lr == 0) {
                int rb = m * 16 + lg * 4;
                vpart[rb + 0][w >> 1] = v0;
                vpart[rb + 1][w >> 1] = v1;
                vpart[rb + 2][w >> 1] = v2;
                vpart[rb + 3][w >> 1] = v3;
            }
        }
    }

    // ---- final deferred vector-message step (last tile) ----
    __syncthreads();
    if (t < TJ) {
        int jp = (NT - 1) * TJ + t;
        float s = vpart[t][0] + vpart[t][1] + vpart[t][2] + vpart[t][3];
        float vg = (s + gb2s) * ewL[t];
        vmx = fmaf(vg, dirxL[jp], vmx);
        vmy = fmaf(vg, diryL[jp], vmy);
        vmz = fmaf(vg, dirzL[jp], vmz);
        vbuf[t * 3 + 0] = vmx;
        vbuf[t * 3 + 1] = vmy;
        vbuf[t * 3 + 2] = vmz;
    }

    // ---- message finalize: reduce 4 row-groups per wave, write per-col ----
    macc0 += __shfl_xor(macc0, 16); macc0 += __shfl_xor(macc0, 32);
    macc1 += __shfl_xor(macc1, 16); macc1 += __shfl_xor(macc1, 32);
    if (l < 16) {
        mpart[m][n0 + l] = macc0;
        mpart[m][n0 + 16 + l] = macc1;
    }
    __syncthreads();

    // ---- scalar-update MLP + LayerNorm (fp32, per row i) ----
    if (t < HH) {
        suin[t] = nf[i * HH + t];
        suin[HH + t] = mpart[0][t] + mpart[1][t];
    }
    __syncthreads();
    if (t < HH) {
        float a = sb1[t];
        for (int k = 0; k < 2 * HH; ++k) a = fmaf(suin[k], sW1[k * HH + t], a);
        hbuf[t] = fast_silu(a);
    }
    __syncthreads();
    float x = 0.f, sx = 0.f, sq = 0.f;
    if (t < HH) {
        float a = sb2[t];
        for (int k = 0; k < HH; ++k) a = fmaf(hbuf[k], sW2[k * HH + t], a);
        x = nf[i * HH + t] + a;
        sx = x;
        sq = x * x;
    }
#pragma unroll
    for (int msk = 1; msk <= 32; msk <<= 1) {
        sx += __shfl_xor(sx, msk);
        sq += __shfl_xor(sq, msk);
    }
    if (t == 0)  { red2[0] = sx; red2[1] = sq; }
    if (t == 64) { red2[2] = sx; red2[3] = sq; }
    __syncthreads();
    if (t < HH) {
        float mean = (red2[0] + red2[2]) * (1.0f / HH);
        float var  = (red2[1] + red2[3]) * (1.0f / HH) - mean * mean;
        out_scalar[i * HH + t] =
            (x - mean) * rsqrtf(var + 1e-5f) * ln_g[t] + ln_b[t];
    }
    if (t < 3) {
        float v = vf[i * 3 + t];
        for (int g = 0; g < TJ; ++g) v += vbuf[g * 3 + t];
        out_vec[i * 3 + t] = v;
    }
}

extern "C" void kernel_launch(void* const* d_in, const int* in_sizes, int n_in,
                              void* d_out, int out_size, void* d_ws, size_t ws_size,
                              hipStream_t stream) {
    const float* nf   = (const float*)d_in[0];
    const float* vf   = (const float*)d_in[1];
    const float* pos  = (const float*)d_in[2];
    const int*   pm   = (const int*)d_in[3];
    const float* cons = (const float*)d_in[4];
    const float* memb = (const float*)d_in[5];
    const float* cata = (const float*)d_in[6];
    const float* eW1  = (const float*)d_in[7];
    const float* eb1  = (const float*)d_in[8];
    const float* eW2  = (const float*)d_in[9];
    const float* eb2  = (const float*)d_in[10];
    const float* sW1  = (const float*)d_in[11];
    const float* sb1  = (const float*)d_in[12];
    const float* sW2  = (const float*)d_in[13];
    const float* sb2  = (const float*)d_in[14];
    const float* gW1  = (const float*)d_in[15];
    const float* gb1  = (const float*)d_in[16];
    const float* gW2  = (const float*)d_in[17];
    const float* gb2  = (const float*)d_in[18];
    const float* lng  = (const float*)d_in[19];
    const float* lnb  = (const float*)d_in[20];

    float* out = (float*)d_out;
    float* out_scalar = out;                     // [768*128]
    float* out_vec    = out + NN * HH;           // [768*3]
    float* out_ew     = out + NN * HH + NN * 3;  // [768*768]

    float* AiP = (float*)d_ws;
    float* AjP = AiP + NN * HH;

    precompute_proj<<<NN, HH, 0, stream>>>(nf, cons, memb, cata, eW1, eb1, AiP, AjP);

    main_kernel<<<NN, THREADS, 0, stream>>>(
        nf, vf, pos, pm, eW1, eW2, eb2, sW1, sb1, sW2, sb2, gW1, gb1, gW2, gb2,
        lng, lnb, AiP, AjP, out_scalar, out_vec, out_ew);
}